// Round 11
// baseline (142.726 us; speedup 1.0000x reference)
//
#include <hip/hip_runtime.h>
#include <stdint.h>

#define GDIM   512
#define HID    150
#define HIDP   160    // HID padded (fp8 row stride for Am/Aa)
#define NROWS  12000
#define KP1    31     // KMAX+1
#define BMP    128    // rows per block (k_proj)
#define BMF    128    // pairs per block (k_fused)

typedef __attribute__((ext_vector_type(4))) float f32x4;
typedef __attribute__((ext_vector_type(2))) float f32x2;
typedef long i64;

__device__ __forceinline__ unsigned short f2bf(float x){
    unsigned int u = __float_as_uint(x);
    return (unsigned short)((u + 0x7fffu + ((u >> 16) & 1u)) >> 16);
}
__device__ __forceinline__ float bf2f(unsigned short u){
    return __uint_as_float(((unsigned int)u) << 16);
}
__device__ __forceinline__ i64 u2l(uint2 v){ return __builtin_bit_cast(i64, v); }
__device__ __forceinline__ f32x4 mfma8(i64 a, i64 b, f32x4 c){
    return __builtin_amdgcn_mfma_f32_16x16x32_fp8_fp8(a, b, c, 0, 0, 0);
}
// fp8x8 elementwise product (f32 math) -> fp8x8
__device__ __forceinline__ uint2 f8mulpk(uint2 m, uint2 a){
    f32x2 m0 = __builtin_amdgcn_cvt_pk_f32_fp8(m.x, false);
    f32x2 m1 = __builtin_amdgcn_cvt_pk_f32_fp8(m.x, true);
    f32x2 m2 = __builtin_amdgcn_cvt_pk_f32_fp8(m.y, false);
    f32x2 m3 = __builtin_amdgcn_cvt_pk_f32_fp8(m.y, true);
    f32x2 a0 = __builtin_amdgcn_cvt_pk_f32_fp8(a.x, false);
    f32x2 a1 = __builtin_amdgcn_cvt_pk_f32_fp8(a.x, true);
    f32x2 a2 = __builtin_amdgcn_cvt_pk_f32_fp8(a.y, false);
    f32x2 a3 = __builtin_amdgcn_cvt_pk_f32_fp8(a.y, true);
    unsigned int r0 = 0, r1 = 0;
    r0 = __builtin_amdgcn_cvt_pk_fp8_f32(m0[0]*a0[0], m0[1]*a0[1], r0, false);
    r0 = __builtin_amdgcn_cvt_pk_fp8_f32(m1[0]*a1[0], m1[1]*a1[1], r0, true);
    r1 = __builtin_amdgcn_cvt_pk_fp8_f32(m2[0]*a2[0], m2[1]*a2[1], r1, false);
    r1 = __builtin_amdgcn_cvt_pk_fp8_f32(m3[0]*a3[0], m3[1]*a3[1], r1, true);
    return (uint2){r0, r1};
}
// async global->LDS, 16B per lane, linear dest (dst = base + lane*16)
__device__ __forceinline__ void glds16(const void* g, void* l){
    __builtin_amdgcn_global_load_lds(
        (const __attribute__((address_space(1))) unsigned int*)g,
        (__attribute__((address_space(3))) unsigned int*)l, 16, 0, 0);
}

// ---------------------------------------------------------------- prep0: hist zero, sentinels, W1/W2 fp8 tables, g8 cast, PhiW, pads
// W18 slice s, K-half hf: W18[s*81920 + hf*40960 + n*256 + (gih^(n&7))*8 + e] = fp8(W1[(s*512+hf*256+gih*8+e)*HID + n])
__global__ void k_prep0(const float* __restrict__ g, unsigned char* __restrict__ g8,
                        int* __restrict__ hist, int4* __restrict__ recs,
                        const float* __restrict__ W1, unsigned char* __restrict__ W18,
                        const float* __restrict__ W2, unsigned char* __restrict__ W28,
                        const float* __restrict__ de, const float* __restrict__ ge,
                        const float* __restrict__ se, const float* __restrict__ b1,
                        const float* __restrict__ W3, const float* __restrict__ b2,
                        unsigned short* __restrict__ PhiW,
                        float* __restrict__ w3p, float* __restrict__ b2p, int P){
    int i = blockIdx.x * blockDim.x + threadIdx.x;
    if (i < NROWS) hist[i] = 0;
    if (i < BMF) recs[P + i] = (int4){0, 0, (int)0x80000000, 0};
    if (i < 30720){
        int s = i / 10240, r = i % 10240;
        int n = r >> 6, gi = r & 63;
        int hf = gi >> 5, gih = gi & 31;
        int gdst = gih ^ (n & 7);
        int k0 = s * 512 + gi * 8;
        float x[8];
        #pragma unroll
        for (int e = 0; e < 8; e++) x[e] = (n < HID) ? W1[(size_t)(k0 + e) * HID + n] : 0.f;
        unsigned int d0 = 0, d1 = 0;
        d0 = __builtin_amdgcn_cvt_pk_fp8_f32(x[0], x[1], d0, false);
        d0 = __builtin_amdgcn_cvt_pk_fp8_f32(x[2], x[3], d0, true);
        d1 = __builtin_amdgcn_cvt_pk_fp8_f32(x[4], x[5], d1, false);
        d1 = __builtin_amdgcn_cvt_pk_fp8_f32(x[6], x[7], d1, true);
        *reinterpret_cast<uint2*>(W18 + (size_t)s * 81920 + hf * 40960 + n * 256 + gdst * 8) = (uint2){d0, d1};
    }
    if (i < 6912){   // W28: 6912 dwords = 27648 B, stride 168
        int n2 = i / 42, kd = (i % 42) * 4;
        float y[4];
        #pragma unroll
        for (int e = 0; e < 4; e++){
            int k = kd + e;
            y[e] = (n2 < HID && k < HID) ? W2[(size_t)k * HID + n2] : 0.f;
        }
        unsigned int d = 0;
        d = __builtin_amdgcn_cvt_pk_fp8_f32(y[0], y[1], d, false);
        d = __builtin_amdgcn_cvt_pk_fp8_f32(y[2], y[3], d, true);
        reinterpret_cast<unsigned int*>(W28)[i] = d;
    }
    if (i < NROWS * 32){
        int lh = i & 3, kt = (i >> 2) & 7, row = i >> 5;
        const float* src = g + (size_t)row * 512 + kt * 64 + lh * 8;
        float4 x0 = *reinterpret_cast<const float4*>(src);
        float4 x1 = *reinterpret_cast<const float4*>(src + 4);
        float4 x2 = *reinterpret_cast<const float4*>(src + 32);
        float4 x3 = *reinterpret_cast<const float4*>(src + 36);
        uint4 o; unsigned int d;
        d = 0; d = __builtin_amdgcn_cvt_pk_fp8_f32(x0.x, x0.y, d, false);
        d = __builtin_amdgcn_cvt_pk_fp8_f32(x0.z, x0.w, d, true);  o.x = d;
        d = 0; d = __builtin_amdgcn_cvt_pk_fp8_f32(x1.x, x1.y, d, false);
        d = __builtin_amdgcn_cvt_pk_fp8_f32(x1.z, x1.w, d, true);  o.y = d;
        d = 0; d = __builtin_amdgcn_cvt_pk_fp8_f32(x2.x, x2.y, d, false);
        d = __builtin_amdgcn_cvt_pk_fp8_f32(x2.z, x2.w, d, true);  o.z = d;
        d = 0; d = __builtin_amdgcn_cvt_pk_fp8_f32(x3.x, x3.y, d, false);
        d = __builtin_amdgcn_cvt_pk_fp8_f32(x3.z, x3.w, d, true);  o.w = d;
        *reinterpret_cast<uint4*>(g8 + (size_t)row * 512 + kt * 64 + lh * 16) = o;
    } else if (i < NROWS * 32 + 33600){
        int j = i - NROWS * 32;
        int c = j / HIDP, h = j - c * HIDP;
        int si = c % 3, gi2 = (c / 3) % 7, di = c / 21;
        float acc = 0.f;
        if (h < HID){
            acc = b1[h];
            #pragma unroll
            for (int dd = 0; dd < 20; dd++) acc += de[di*20 + dd] * W1[(size_t)(1536 + dd) * HID + h];
            #pragma unroll
            for (int dd = 0; dd < 20; dd++) acc += ge[gi2*20 + dd] * W1[(size_t)(1556 + dd) * HID + h];
            #pragma unroll
            for (int dd = 0; dd < 20; dd++) acc += se[si*20 + dd] * W1[(size_t)(1576 + dd) * HID + h];
        }
        PhiW[c * HIDP + h] = f2bf(acc);
    } else if (i < NROWS * 32 + 33600 + HIDP){
        int h = i - NROWS * 32 - 33600;
        w3p[h] = (h < HID) ? W3[h] : 0.f;
        b2p[h] = (h < HID) ? b2[h] : 0.f;
    }
}

// ---------------------------------------------------------------- sort kernels
__global__ void k_hist(const int* __restrict__ mid, int* __restrict__ hist, int P){
    int p = blockIdx.x * blockDim.x + threadIdx.x;
    if (p < P) atomicAdd(&hist[mid[p]], 1);
}
__global__ void k_scan(const int* __restrict__ hist, int* __restrict__ offsw, int nb){
    __shared__ int part[1024];
    int t = threadIdx.x;
    int chunk = (nb + 1023) / 1024;
    int lo = t * chunk, hi = lo + chunk; if (hi > nb) hi = nb;
    int s = 0;
    for (int b = lo; b < hi; b++) s += hist[b];
    part[t] = s;
    __syncthreads();
    for (int d = 1; d < 1024; d <<= 1){
        int v = (t >= d) ? part[t - d] : 0;
        __syncthreads();
        part[t] += v;
        __syncthreads();
    }
    int run = part[t] - s;
    for (int b = lo; b < hi; b++){ offsw[b] = run; run += hist[b]; }
}
__global__ void k_scatter(const int* __restrict__ mident, const int* __restrict__ antid,
                          const int* __restrict__ di, const int* __restrict__ gi, const int* __restrict__ si,
                          const int* __restrict__ seg, const int* __restrict__ pos, const float* __restrict__ ms,
                          int* __restrict__ offsw, int4* __restrict__ recs, int P){
    int p = blockIdx.x * blockDim.x + threadIdx.x;
    if (p >= P) return;
    int m = mident[p], a = antid[p];
    int idx = atomicAdd(&offsw[m], 1);
    int combo = (di[p] * 7 + gi[p]) * 3 + si[p];
    int meta = (combo << 19) | (seg[p] << 5) | pos[p];
    int4 r; r.x = m; r.y = a; r.z = meta; r.w = __float_as_int(ms[m] + ms[a]);
    recs[idx] = r;
}

// ================================================================ phase 1: Am/Aa projections — 40KB K-split W LDS, R7-style prefetch
__global__ __launch_bounds__(256) void k_proj(const unsigned char* __restrict__ g8,
                                              const unsigned char* __restrict__ W18,
                                              unsigned char* __restrict__ out){
    __shared__ __align__(16) char smem[40960];
    const unsigned char* Wt = W18 + (size_t)blockIdx.y * 81920;
    unsigned char* outh = out + (size_t)blockIdx.y * NROWS * HIDP;
    int tid = threadIdx.x, lane = tid & 63, w = tid >> 6;
    int l15 = lane & 15, lh = lane >> 4;
    int swz8 = (l15 & 7) << 3;
    int row0 = blockIdx.x * BMP;

    int r0 = row0 + 32*w + l15;       int r0c = (r0 < NROWS) ? r0 : NROWS - 1;
    int r1 = r0 + 16;                 int r1c = (r1 < NROWS) ? r1 : NROWS - 1;
    const unsigned char* gp0 = g8 + (size_t)r0c * GDIM + lh * 16;
    const unsigned char* gp1 = g8 + (size_t)r1c * GDIM + lh * 16;

    f32x4 acc1[10][2];
    #pragma unroll
    for (int t = 0; t < 10; t++){ acc1[t][0] = (f32x4){0,0,0,0}; acc1[t][1] = (f32x4){0,0,0,0}; }

    #pragma unroll
    for (int hf = 0; hf < 2; hf++){
        // stage 40KB K-half: 40 chunks, 10/wave
        #pragma unroll
        for (int i = 0; i < 10; i++){
            int c = w * 10 + i;
            glds16(Wt + hf * 40960 + c * 1024 + lane * 16, smem + c * 1024);
        }
        asm volatile("s_waitcnt vmcnt(0)" ::: "memory");
        __builtin_amdgcn_s_barrier();

        const unsigned char* a0p = gp0 + hf * 256;
        const unsigned char* a1p = gp1 + hf * 256;
        uint4 R0 = *reinterpret_cast<const uint4*>(a0p);
        uint4 R1 = *reinterpret_cast<const uint4*>(a1p);
        #pragma unroll
        for (int kt = 0; kt < 4; kt++){
            uint4 N0, N1;
            if (kt < 3){
                N0 = *reinterpret_cast<const uint4*>(a0p + (kt+1)*64);
                N1 = *reinterpret_cast<const uint4*>(a1p + (kt+1)*64);
            }
            i64 a00 = u2l((uint2){R0.x, R0.y}), a01 = u2l((uint2){R0.z, R0.w});
            i64 a10 = u2l((uint2){R1.x, R1.y}), a11 = u2l((uint2){R1.z, R1.w});
            #pragma unroll
            for (int t = 0; t < 10; t++){
                int rowb = (t*16 + l15) * 256;
                i64 b0 = *reinterpret_cast<const i64*>(&smem[rowb + ((kt*64 +  0 + lh*8) ^ swz8)]);
                i64 b1 = *reinterpret_cast<const i64*>(&smem[rowb + ((kt*64 + 32 + lh*8) ^ swz8)]);
                acc1[t][0] = mfma8(b0, a00, acc1[t][0]);
                acc1[t][1] = mfma8(b0, a10, acc1[t][1]);
                acc1[t][0] = mfma8(b1, a01, acc1[t][0]);
                acc1[t][1] = mfma8(b1, a11, acc1[t][1]);
            }
            R0 = N0; R1 = N1;
        }
        // all waves done reading this half before it is overwritten
        asm volatile("s_waitcnt lgkmcnt(0)" ::: "memory");
        __builtin_amdgcn_s_barrier();
    }

    // epilogue: 4 consecutive h per lane -> fp8 dword stores
    #pragma unroll
    for (int rf = 0; rf < 2; rf++){
        int row = row0 + 32*w + 16*rf + l15;
        if (row < NROWS){
            #pragma unroll
            for (int t = 0; t < 10; t++){
                f32x4 a = acc1[t][rf];
                unsigned int dw = 0;
                dw = __builtin_amdgcn_cvt_pk_fp8_f32(a[0], a[1], dw, false);
                dw = __builtin_amdgcn_cvt_pk_fp8_f32(a[2], a[3], dw, true);
                *reinterpret_cast<unsigned int*>(outh + (size_t)row * HIDP + 16*t + 4*lh) = dw;
            }
        }
    }
}

// ================================================================ fused pair scorer — 40KB K-split W LDS, W2 from global, XCD swizzle
__global__ __launch_bounds__(256) void k_fused(
    const unsigned char* __restrict__ g8,
    const unsigned char* __restrict__ W1c8, const unsigned char* __restrict__ W28,
    const unsigned short* __restrict__ PhiW, const unsigned char* __restrict__ Am,
    const unsigned char* __restrict__ Aa,
    const float* __restrict__ w3p, const float* __restrict__ b2p, const float* __restrict__ b3,
    const int4* __restrict__ recs,
    float* __restrict__ dense)
{
    __shared__ __align__(16) char smem[40960];   // W1c K-half [160][256] fp8; later H1 [0,21504)
    int tid = threadIdx.x, lane = tid & 63, w = tid >> 6;
    int l15 = lane & 15, lh = lane >> 4;
    int swz8 = (l15 & 7) << 3;

    // bijective XCD swizzle (m204)
    int nwg = gridDim.x, orig = blockIdx.x, bid = orig;
    if (nwg >= 8){
        int q = nwg >> 3, r = nwg & 7;
        int xcd = orig & 7, lid = orig >> 3;
        bid = (xcd < r ? xcd * (q + 1) : r * (q + 1) + (xcd - r) * q) + lid;
    }
    int p0 = bid * BMF;

    int4 rec0 = recs[p0 + 32*w + l15];
    int4 rec1 = recs[p0 + 32*w + 16 + l15];

    const unsigned char* gm0 = g8 + (size_t)rec0.x * GDIM + lh * 16;
    const unsigned char* ga0 = g8 + (size_t)rec0.y * GDIM + lh * 16;
    const unsigned char* gm1 = g8 + (size_t)rec1.x * GDIM + lh * 16;
    const unsigned char* ga1 = g8 + (size_t)rec1.y * GDIM + lh * 16;

    f32x4 acc1[10][2];
    #pragma unroll
    for (int t = 0; t < 10; t++){ acc1[t][0] = (f32x4){0,0,0,0}; acc1[t][1] = (f32x4){0,0,0,0}; }

    #pragma unroll
    for (int hf = 0; hf < 2; hf++){
        // stage 40KB K-half of W1c: 40 chunks, 10/wave
        #pragma unroll
        for (int i = 0; i < 10; i++){
            int c = w * 10 + i;
            glds16(W1c8 + hf * 40960 + c * 1024 + lane * 16, smem + c * 1024);
        }
        asm volatile("s_waitcnt vmcnt(0)" ::: "memory");
        __builtin_amdgcn_s_barrier();

        const unsigned char* m0p = gm0 + hf * 256;
        const unsigned char* a0p = ga0 + hf * 256;
        const unsigned char* m1p = gm1 + hf * 256;
        const unsigned char* a1p = ga1 + hf * 256;
        uint4 Rm0 = *reinterpret_cast<const uint4*>(m0p);
        uint4 Ra0 = *reinterpret_cast<const uint4*>(a0p);
        uint4 Rm1 = *reinterpret_cast<const uint4*>(m1p);
        uint4 Ra1 = *reinterpret_cast<const uint4*>(a1p);
        #pragma unroll
        for (int kt = 0; kt < 4; kt++){
            uint4 Nm0, Na0, Nm1, Na1;
            if (kt < 3){
                Nm0 = *reinterpret_cast<const uint4*>(m0p + (kt+1)*64);
                Na0 = *reinterpret_cast<const uint4*>(a0p + (kt+1)*64);
                Nm1 = *reinterpret_cast<const uint4*>(m1p + (kt+1)*64);
                Na1 = *reinterpret_cast<const uint4*>(a1p + (kt+1)*64);
            }
            uint2 p00 = f8mulpk((uint2){Rm0.x, Rm0.y}, (uint2){Ra0.x, Ra0.y});
            uint2 p01 = f8mulpk((uint2){Rm0.z, Rm0.w}, (uint2){Ra0.z, Ra0.w});
            uint2 p10 = f8mulpk((uint2){Rm1.x, Rm1.y}, (uint2){Ra1.x, Ra1.y});
            uint2 p11 = f8mulpk((uint2){Rm1.z, Rm1.w}, (uint2){Ra1.z, Ra1.w});
            i64 lp00 = u2l(p00), lp01 = u2l(p01), lp10 = u2l(p10), lp11 = u2l(p11);
            #pragma unroll
            for (int t = 0; t < 10; t++){
                int rowb = (t*16 + l15) * 256;
                i64 b0 = *reinterpret_cast<const i64*>(&smem[rowb + ((kt*64 +  0 + lh*8) ^ swz8)]);
                i64 b1 = *reinterpret_cast<const i64*>(&smem[rowb + ((kt*64 + 32 + lh*8) ^ swz8)]);
                acc1[t][0] = mfma8(b0, lp00, acc1[t][0]);
                acc1[t][1] = mfma8(b0, lp10, acc1[t][1]);
                acc1[t][0] = mfma8(b1, lp01, acc1[t][0]);
                acc1[t][1] = mfma8(b1, lp11, acc1[t][1]);
            }
            Rm0 = Nm0; Ra0 = Na0; Rm1 = Nm1; Ra1 = Na1;
        }
        // all waves done reading this half before overwrite (half1 stage or H1 writes)
        asm volatile("s_waitcnt lgkmcnt(0)" ::: "memory");
        __builtin_amdgcn_s_barrier();
    }

    // ---- epilogue 1: + Am + Aa + PhiW, relu, fp8-pack -> H1 (own-wave slab, stride 168)
    #pragma unroll
    for (int rf = 0; rf < 2; rf++){
        int4 rc = rf ? rec1 : rec0;
        int pr = 32*w + 16*rf + l15;
        const unsigned char* amp = Am + (size_t)rc.x * HIDP;
        const unsigned char* aap = Aa + (size_t)rc.y * HIDP;
        int combo = (rc.z >> 19) & 0xFF;
        const unsigned short* php = PhiW + (size_t)combo * HIDP;
        char* h1row = smem + pr * 168;
        #pragma unroll
        for (int t = 0; t < 10; t++){
            int h0 = 16*t + 4*lh;
            unsigned int amd = *reinterpret_cast<const unsigned int*>(amp + h0);
            unsigned int aad = *reinterpret_cast<const unsigned int*>(aap + h0);
            ushort4 ph4 = *reinterpret_cast<const ushort4*>(php + h0);
            f32x2 amL = __builtin_amdgcn_cvt_pk_f32_fp8(amd, false);
            f32x2 amH = __builtin_amdgcn_cvt_pk_f32_fp8(amd, true);
            f32x2 aaL = __builtin_amdgcn_cvt_pk_f32_fp8(aad, false);
            f32x2 aaH = __builtin_amdgcn_cvt_pk_f32_fp8(aad, true);
            f32x4 a = acc1[t][rf];
            float v0 = fmaxf(a[0] + amL[0] + aaL[0] + bf2f(ph4.x), 0.f);
            float v1 = fmaxf(a[1] + amL[1] + aaL[1] + bf2f(ph4.y), 0.f);
            float v2 = fmaxf(a[2] + amH[0] + aaH[0] + bf2f(ph4.z), 0.f);
            float v3 = fmaxf(a[3] + amH[1] + aaH[1] + bf2f(ph4.w), 0.f);
            unsigned int dw = 0;
            dw = __builtin_amdgcn_cvt_pk_fp8_f32(v0, v1, dw, false);
            dw = __builtin_amdgcn_cvt_pk_fp8_f32(v2, v3, dw, true);
            *reinterpret_cast<unsigned int*>(h1row + h0) = dw;
        }
    }
    // GEMM2 reads only own-wave H1 slab -> no barrier needed (compiler inserts lgkm waits)

    // ---- GEMM2: H2 = W2(global, L2-resident) x H1(LDS own slab), fp8 MFMA
    f32x4 acc2[10][2];
    #pragma unroll
    for (int t = 0; t < 10; t++){ acc2[t][0] = (f32x4){0,0,0,0}; acc2[t][1] = (f32x4){0,0,0,0}; }
    #pragma unroll
    for (int k2 = 0; k2 < 5; k2++){
        i64 h0f = *reinterpret_cast<const i64*>(smem + (32*w + l15)      * 168 + k2*32 + lh*8);
        i64 h1f = *reinterpret_cast<const i64*>(smem + (32*w + 16 + l15) * 168 + k2*32 + lh*8);
        #pragma unroll
        for (int t = 0; t < 10; t++){
            i64 wf = *reinterpret_cast<const i64*>(W28 + (16*t + l15) * 168 + k2*32 + lh*8);
            acc2[t][0] = mfma8(wf, h0f, acc2[t][0]);
            acc2[t][1] = mfma8(wf, h1f, acc2[t][1]);
        }
    }

    // ---- epilogue 2: relu(+b2), dot W3, + ms sum, scatter
    float b3v = b3[0];
    #pragma unroll
    for (int rf = 0; rf < 2; rf++){
        int4 rc = rf ? rec1 : rec0;
        float s = 0.f;
        #pragma unroll
        for (int t = 0; t < 10; t++){
            f32x4 w3v = *reinterpret_cast<const f32x4*>(w3p + 16*t + 4*lh);
            f32x4 b2v = *reinterpret_cast<const f32x4*>(b2p + 16*t + 4*lh);
            f32x4 a = acc2[t][rf];
            s += fmaxf(a[0] + b2v[0], 0.f) * w3v[0];
            s += fmaxf(a[1] + b2v[1], 0.f) * w3v[1];
            s += fmaxf(a[2] + b2v[2], 0.f) * w3v[2];
            s += fmaxf(a[3] + b2v[3], 0.f) * w3v[3];
        }
        s += __shfl_xor(s, 16);
        s += __shfl_xor(s, 32);
        if (!(rc.z & 0x80000000) && lh == 0){
            float val = s + b3v + __int_as_float(rc.w);
            dense[(size_t)((rc.z >> 5) & 0x3FFF) * KP1 + (rc.z & 31)] = val;
        }
    }
}

// ---------------------------------------------------------------- phase 4: segment softmax
__global__ void k_softmax(const float* __restrict__ dense, const int* __restrict__ seg_lengths,
                          float* __restrict__ out, int S){
    int wid = threadIdx.x >> 6, lane = threadIdx.x & 63;
    int s = blockIdx.x * 4 + wid;
    if (s >= S) return;
    int len = seg_lengths[s];
    float ninf = -__builtin_inff();
    float val = ninf;
    if (lane < KP1) val = (lane < len) ? dense[(size_t)s * KP1 + lane] : ((lane == len) ? 0.f : ninf);
    float m = val;
    #pragma unroll
    for (int msk = 1; msk < 64; msk <<= 1) m = fmaxf(m, __shfl_xor(m, msk));
    float e = expf(val - m);
    float sum = e;
    #pragma unroll
    for (int msk = 1; msk < 64; msk <<= 1) sum += __shfl_xor(sum, msk);
    if (lane < KP1) out[(size_t)s * KP1 + lane] = (lane > len) ? 1000.f : (e / sum);
}

// ---------------------------------------------------------------- launch
extern "C" void kernel_launch(void* const* d_in, const int* in_sizes, int n_in,
                              void* d_out, int out_size, void* d_ws, size_t ws_size,
                              hipStream_t stream){
    const float* g_i        = (const float*)d_in[0];
    const float* ms         = (const float*)d_in[1];
    const float* dist_emb   = (const float*)d_in[2];
    const float* genre_emb  = (const float*)d_in[3];
    const float* spk_emb    = (const float*)d_in[4];
    const float* W1         = (const float*)d_in[5];
    const float* b1         = (const float*)d_in[6];
    const float* W2         = (const float*)d_in[7];
    const float* b2         = (const float*)d_in[8];
    const float* W3         = (const float*)d_in[9];
    const float* b3         = (const float*)d_in[10];
    const int* mention_ids  = (const int*)d_in[11];
    const int* antecedent_ids = (const int*)d_in[12];
    const int* dist_idx     = (const int*)d_in[13];
    const int* genre_idx    = (const int*)d_in[14];
    const int* spk_idx      = (const int*)d_in[15];
    const int* seg_ids      = (const int*)d_in[16];
    const int* pos_in_seg   = (const int*)d_in[17];
    const int* seg_lengths  = (const int*)d_in[18];
    int P = in_sizes[11];
    int S = in_sizes[18];

    char* ws = (char*)d_ws;
    unsigned char* W18   = (unsigned char*)(ws + 0);         // 3 x 81920 = 245760
    unsigned char* W28   = (unsigned char*)(ws + 245760);    // 27648   -> 273408
    unsigned short* PhiW = (unsigned short*)(ws + 273408);   // 67200   -> 340608
    float* w3pad         = (float*)(ws + 340608);            // 640     -> 341248
    float* b2pad         = (float*)(ws + 341248);            // 640     -> 341888
    unsigned char* g8    = (unsigned char*)(ws + 341888);    // 6144000 -> 6485888
    unsigned char* Am8   = (unsigned char*)(ws + 6485888);   // 1920000 -> 8405888
    unsigned char* Aa8   = (unsigned char*)(ws + 8405888);   // 1920000 -> 10325888
    int* hist            = (int*)(ws + 10325888);            // 48000   -> 10373888
    int* offsw           = (int*)(ws + 10373888);            // 48000   -> 10421888
    int4* recs           = (int4*)(ws + 10421888);           // (P+128)*16 -> <13000192
    float* dense         = (float*)(ws + 13000192);          // 10001*31*4

    int prep_threads = NROWS * 32 + 33600 + HIDP;
    k_prep0<<<(prep_threads + 255)/256, 256, 0, stream>>>(g_i, g8, hist, recs, W1, W18, W2, W28,
        dist_emb, genre_emb, spk_emb, b1, W3, b2, PhiW, w3pad, b2pad, P);
    k_hist<<<(P + 255)/256, 256, 0, stream>>>(mention_ids, hist, P);
    k_scan<<<1, 1024, 0, stream>>>(hist, offsw, NROWS);
    k_scatter<<<(P + 255)/256, 256, 0, stream>>>(mention_ids, antecedent_ids, dist_idx, genre_idx,
        spk_idx, seg_ids, pos_in_seg, ms, offsw, recs, P);

    // row projections Am / Aa (fp8 out; y selects W1a/W1b slice and output half)
    k_proj<<<dim3((NROWS + BMP - 1)/BMP, 2), 256, 0, stream>>>(g8, W18, Am8);

    // fused pair scorer (256 threads, 128 pairs/block)
    k_fused<<<(P + BMF - 1)/BMF, 256, 0, stream>>>(g8, W18 + 2*81920, W28, PhiW,
        Am8, Aa8, w3pad, b2pad, b3, recs, dense);

    // segment softmax
    k_softmax<<<(S + 3)/4, 256, 0, stream>>>(dense, seg_lengths, (float*)d_out, S);
}

// Round 12
// 111.435 us; speedup vs baseline: 1.2808x; 1.2808x over previous
//
#include <hip/hip_runtime.h>
#include <stdint.h>

#define GDIM   512
#define HID    150
#define HIDP   160    // HID padded (fp8 row stride for Am/Aa)
#define NROWS  12000
#define KP1    31     // KMAX+1
#define BMP    128    // rows per block (k_proj)
#define BMF    128    // pairs per block (k_fused)

typedef __attribute__((ext_vector_type(4))) float f32x4;
typedef __attribute__((ext_vector_type(2))) float f32x2;
typedef long i64;

__device__ __forceinline__ unsigned short f2bf(float x){
    unsigned int u = __float_as_uint(x);
    return (unsigned short)((u + 0x7fffu + ((u >> 16) & 1u)) >> 16);
}
__device__ __forceinline__ float bf2f(unsigned short u){
    return __uint_as_float(((unsigned int)u) << 16);
}
__device__ __forceinline__ i64 u2l(uint2 v){ return __builtin_bit_cast(i64, v); }
__device__ __forceinline__ f32x4 mfma8(i64 a, i64 b, f32x4 c){
    return __builtin_amdgcn_mfma_f32_16x16x32_fp8_fp8(a, b, c, 0, 0, 0);
}
// fp8x8 elementwise product (f32 math) -> fp8x8
__device__ __forceinline__ uint2 f8mulpk(uint2 m, uint2 a){
    f32x2 m0 = __builtin_amdgcn_cvt_pk_f32_fp8(m.x, false);
    f32x2 m1 = __builtin_amdgcn_cvt_pk_f32_fp8(m.x, true);
    f32x2 m2 = __builtin_amdgcn_cvt_pk_f32_fp8(m.y, false);
    f32x2 m3 = __builtin_amdgcn_cvt_pk_f32_fp8(m.y, true);
    f32x2 a0 = __builtin_amdgcn_cvt_pk_f32_fp8(a.x, false);
    f32x2 a1 = __builtin_amdgcn_cvt_pk_f32_fp8(a.x, true);
    f32x2 a2 = __builtin_amdgcn_cvt_pk_f32_fp8(a.y, false);
    f32x2 a3 = __builtin_amdgcn_cvt_pk_f32_fp8(a.y, true);
    unsigned int r0 = 0, r1 = 0;
    r0 = __builtin_amdgcn_cvt_pk_fp8_f32(m0[0]*a0[0], m0[1]*a0[1], r0, false);
    r0 = __builtin_amdgcn_cvt_pk_fp8_f32(m1[0]*a1[0], m1[1]*a1[1], r0, true);
    r1 = __builtin_amdgcn_cvt_pk_fp8_f32(m2[0]*a2[0], m2[1]*a2[1], r1, false);
    r1 = __builtin_amdgcn_cvt_pk_fp8_f32(m3[0]*a3[0], m3[1]*a3[1], r1, true);
    return (uint2){r0, r1};
}
// async global->LDS, 16B per lane, linear dest (dst = base + lane*16)
__device__ __forceinline__ void glds16(const void* g, void* l){
    __builtin_amdgcn_global_load_lds(
        (const __attribute__((address_space(1))) unsigned int*)g,
        (__attribute__((address_space(3))) unsigned int*)l, 16, 0, 0);
}

// ---------------------------------------------------------------- prep0: hist zero, sentinels, W1/W2 fp8 tables (full-512 layout), g8, PhiW, pads
__global__ void k_prep0(const float* __restrict__ g, unsigned char* __restrict__ g8,
                        int* __restrict__ hist, int4* __restrict__ recs,
                        const float* __restrict__ W1, unsigned char* __restrict__ W18,
                        const float* __restrict__ W2, unsigned char* __restrict__ W28,
                        const float* __restrict__ de, const float* __restrict__ ge,
                        const float* __restrict__ se, const float* __restrict__ b1,
                        const float* __restrict__ W3, const float* __restrict__ b2,
                        unsigned short* __restrict__ PhiW,
                        float* __restrict__ w3p, float* __restrict__ b2p, int P){
    int i = blockIdx.x * blockDim.x + threadIdx.x;
    if (i < NROWS) hist[i] = 0;
    if (i < BMF) recs[P + i] = (int4){0, 0, (int)0x80000000, 0};
    if (i < 30720){
        int s = i / 10240, r = i % 10240;
        int n = r >> 6, gi = r & 63;
        int gdst = gi ^ (n & 7);
        int k0 = s * 512 + gi * 8;
        float x[8];
        #pragma unroll
        for (int e = 0; e < 8; e++) x[e] = (n < HID) ? W1[(size_t)(k0 + e) * HID + n] : 0.f;
        unsigned int d0 = 0, d1 = 0;
        d0 = __builtin_amdgcn_cvt_pk_fp8_f32(x[0], x[1], d0, false);
        d0 = __builtin_amdgcn_cvt_pk_fp8_f32(x[2], x[3], d0, true);
        d1 = __builtin_amdgcn_cvt_pk_fp8_f32(x[4], x[5], d1, false);
        d1 = __builtin_amdgcn_cvt_pk_fp8_f32(x[6], x[7], d1, true);
        *reinterpret_cast<uint2*>(W18 + (size_t)s * 81920 + n * 512 + gdst * 8) = (uint2){d0, d1};
    }
    if (i < 6912){   // W28: 6912 dwords = 27648 B, row stride 168
        int n2 = i / 42, kd = (i % 42) * 4;
        float y[4];
        #pragma unroll
        for (int e = 0; e < 4; e++){
            int k = kd + e;
            y[e] = (n2 < HID && k < HID) ? W2[(size_t)k * HID + n2] : 0.f;
        }
        unsigned int d = 0;
        d = __builtin_amdgcn_cvt_pk_fp8_f32(y[0], y[1], d, false);
        d = __builtin_amdgcn_cvt_pk_fp8_f32(y[2], y[3], d, true);
        reinterpret_cast<unsigned int*>(W28)[i] = d;
    }
    if (i < NROWS * 32){
        int lh = i & 3, kt = (i >> 2) & 7, row = i >> 5;
        const float* src = g + (size_t)row * 512 + kt * 64 + lh * 8;
        float4 x0 = *reinterpret_cast<const float4*>(src);
        float4 x1 = *reinterpret_cast<const float4*>(src + 4);
        float4 x2 = *reinterpret_cast<const float4*>(src + 32);
        float4 x3 = *reinterpret_cast<const float4*>(src + 36);
        uint4 o; unsigned int d;
        d = 0; d = __builtin_amdgcn_cvt_pk_fp8_f32(x0.x, x0.y, d, false);
        d = __builtin_amdgcn_cvt_pk_fp8_f32(x0.z, x0.w, d, true);  o.x = d;
        d = 0; d = __builtin_amdgcn_cvt_pk_fp8_f32(x1.x, x1.y, d, false);
        d = __builtin_amdgcn_cvt_pk_fp8_f32(x1.z, x1.w, d, true);  o.y = d;
        d = 0; d = __builtin_amdgcn_cvt_pk_fp8_f32(x2.x, x2.y, d, false);
        d = __builtin_amdgcn_cvt_pk_fp8_f32(x2.z, x2.w, d, true);  o.z = d;
        d = 0; d = __builtin_amdgcn_cvt_pk_fp8_f32(x3.x, x3.y, d, false);
        d = __builtin_amdgcn_cvt_pk_fp8_f32(x3.z, x3.w, d, true);  o.w = d;
        *reinterpret_cast<uint4*>(g8 + (size_t)row * 512 + kt * 64 + lh * 16) = o;
    } else if (i < NROWS * 32 + 33600){
        int j = i - NROWS * 32;
        int c = j / HIDP, h = j - c * HIDP;
        int si = c % 3, gi2 = (c / 3) % 7, di = c / 21;
        float acc = 0.f;
        if (h < HID){
            acc = b1[h];
            #pragma unroll
            for (int dd = 0; dd < 20; dd++) acc += de[di*20 + dd] * W1[(size_t)(1536 + dd) * HID + h];
            #pragma unroll
            for (int dd = 0; dd < 20; dd++) acc += ge[gi2*20 + dd] * W1[(size_t)(1556 + dd) * HID + h];
            #pragma unroll
            for (int dd = 0; dd < 20; dd++) acc += se[si*20 + dd] * W1[(size_t)(1576 + dd) * HID + h];
        }
        PhiW[c * HIDP + h] = f2bf(acc);
    } else if (i < NROWS * 32 + 33600 + HIDP){
        int h = i - NROWS * 32 - 33600;
        w3p[h] = (h < HID) ? W3[h] : 0.f;
        b2p[h] = (h < HID) ? b2[h] : 0.f;
    }
}

// ---------------------------------------------------------------- sort kernels
__global__ void k_hist(const int* __restrict__ mid, int* __restrict__ hist, int P){
    int p = blockIdx.x * blockDim.x + threadIdx.x;
    if (p < P) atomicAdd(&hist[mid[p]], 1);
}
__global__ void k_scan(const int* __restrict__ hist, int* __restrict__ offsw, int nb){
    __shared__ int part[1024];
    int t = threadIdx.x;
    int chunk = (nb + 1023) / 1024;
    int lo = t * chunk, hi = lo + chunk; if (hi > nb) hi = nb;
    int s = 0;
    for (int b = lo; b < hi; b++) s += hist[b];
    part[t] = s;
    __syncthreads();
    for (int d = 1; d < 1024; d <<= 1){
        int v = (t >= d) ? part[t - d] : 0;
        __syncthreads();
        part[t] += v;
        __syncthreads();
    }
    int run = part[t] - s;
    for (int b = lo; b < hi; b++){ offsw[b] = run; run += hist[b]; }
}
__global__ void k_scatter(const int* __restrict__ mident, const int* __restrict__ antid,
                          const int* __restrict__ di, const int* __restrict__ gi, const int* __restrict__ si,
                          const int* __restrict__ seg, const int* __restrict__ pos, const float* __restrict__ ms,
                          int* __restrict__ offsw, int4* __restrict__ recs, int P){
    int p = blockIdx.x * blockDim.x + threadIdx.x;
    if (p >= P) return;
    int m = mident[p], a = antid[p];
    int idx = atomicAdd(&offsw[m], 1);
    int combo = (di[p] * 7 + gi[p]) * 3 + si[p];
    int meta = (combo << 19) | (seg[p] << 5) | pos[p];
    int4 r; r.x = m; r.y = a; r.z = meta; r.w = __float_as_int(ms[m] + ms[a]);
    recs[idx] = r;
}

// ================================================================ phase 1: Am/Aa projections — static 80KB W LDS, barrier-free K-loop (R7-proven)
__global__ __launch_bounds__(256) void k_proj(const unsigned char* __restrict__ g8,
                                              const unsigned char* __restrict__ W18,
                                              unsigned char* __restrict__ out){
    __shared__ __align__(16) char smem[81920];
    const unsigned char* Wt = W18 + (size_t)blockIdx.y * 81920;
    unsigned char* outh = out + (size_t)blockIdx.y * NROWS * HIDP;
    int tid = threadIdx.x, lane = tid & 63, w = tid >> 6;
    int l15 = lane & 15, lh = lane >> 4;
    int swz8 = (l15 & 7) << 3;
    int row0 = blockIdx.x * BMP;

    int r0 = row0 + 32*w + l15;       int r0c = (r0 < NROWS) ? r0 : NROWS - 1;
    int r1 = r0 + 16;                 int r1c = (r1 < NROWS) ? r1 : NROWS - 1;
    const unsigned char* gp0 = g8 + (size_t)r0c * GDIM + lh * 16;
    const unsigned char* gp1 = g8 + (size_t)r1c * GDIM + lh * 16;

    // stage 80KB W slice once: 80 chunks, 20 per wave
    #pragma unroll
    for (int i = 0; i < 20; i++){
        int c = w * 20 + i;
        glds16(Wt + c * 1024 + lane * 16, smem + c * 1024);
    }

    f32x4 acc1[10][2];
    #pragma unroll
    for (int t = 0; t < 10; t++){ acc1[t][0] = (f32x4){0,0,0,0}; acc1[t][1] = (f32x4){0,0,0,0}; }

    asm volatile("s_waitcnt vmcnt(0)" ::: "memory");
    __builtin_amdgcn_s_barrier();

    uint4 R0 = *reinterpret_cast<const uint4*>(gp0);
    uint4 R1 = *reinterpret_cast<const uint4*>(gp1);
    #pragma unroll
    for (int kt = 0; kt < 8; kt++){
        uint4 N0, N1;
        if (kt < 7){
            N0 = *reinterpret_cast<const uint4*>(gp0 + (kt+1)*64);
            N1 = *reinterpret_cast<const uint4*>(gp1 + (kt+1)*64);
        }
        i64 a00 = u2l((uint2){R0.x, R0.y}), a01 = u2l((uint2){R0.z, R0.w});
        i64 a10 = u2l((uint2){R1.x, R1.y}), a11 = u2l((uint2){R1.z, R1.w});
        __builtin_amdgcn_s_setprio(1);
        #pragma unroll
        for (int t = 0; t < 10; t++){
            int rowb = (t*16 + l15) * 512;
            i64 b0 = *reinterpret_cast<const i64*>(&smem[rowb + ((kt*64 +  0 + lh*8) ^ swz8)]);
            i64 b1 = *reinterpret_cast<const i64*>(&smem[rowb + ((kt*64 + 32 + lh*8) ^ swz8)]);
            acc1[t][0] = mfma8(b0, a00, acc1[t][0]);
            acc1[t][1] = mfma8(b0, a10, acc1[t][1]);
            acc1[t][0] = mfma8(b1, a01, acc1[t][0]);
            acc1[t][1] = mfma8(b1, a11, acc1[t][1]);
        }
        __builtin_amdgcn_s_setprio(0);
        R0 = N0; R1 = N1;
    }

    // epilogue: 4 consecutive h per lane -> fp8 dword stores
    #pragma unroll
    for (int rf = 0; rf < 2; rf++){
        int row = row0 + 32*w + 16*rf + l15;
        if (row < NROWS){
            #pragma unroll
            for (int t = 0; t < 10; t++){
                f32x4 a = acc1[t][rf];
                unsigned int dw = 0;
                dw = __builtin_amdgcn_cvt_pk_fp8_f32(a[0], a[1], dw, false);
                dw = __builtin_amdgcn_cvt_pk_fp8_f32(a[2], a[3], dw, true);
                *reinterpret_cast<unsigned int*>(outh + (size_t)row * HIDP + 16*t + 4*lh) = dw;
            }
        }
    }
}

// ================================================================ fused pair scorer — static 80KB W LDS, barrier-free K-loop (R7-proven) + XCD swizzle + setprio
__global__ __launch_bounds__(256) void k_fused(
    const unsigned char* __restrict__ g8,
    const unsigned char* __restrict__ W1c8, const unsigned char* __restrict__ W28,
    const unsigned short* __restrict__ PhiW, const unsigned char* __restrict__ Am,
    const unsigned char* __restrict__ Aa,
    const float* __restrict__ w3p, const float* __restrict__ b2p, const float* __restrict__ b3,
    const int4* __restrict__ recs,
    float* __restrict__ dense)
{
    __shared__ __align__(16) char smem[81920];   // W1c [160][512] fp8; later H1 [0,21504) + W2 [21504,49152)
    int tid = threadIdx.x, lane = tid & 63, w = tid >> 6;
    int l15 = lane & 15, lh = lane >> 4;
    int swz8 = (l15 & 7) << 3;

    // bijective XCD swizzle (m204)
    int nwg = gridDim.x, orig = blockIdx.x, bid = orig;
    if (nwg >= 8){
        int q = nwg >> 3, r = nwg & 7;
        int xcd = orig & 7, lid = orig >> 3;
        bid = (xcd < r ? xcd * (q + 1) : r * (q + 1) + (xcd - r) * q) + lid;
    }
    int p0 = bid * BMF;

    int4 rec0 = recs[p0 + 32*w + l15];
    int4 rec1 = recs[p0 + 32*w + 16 + l15];

    const unsigned char* gm0 = g8 + (size_t)rec0.x * GDIM + lh * 16;
    const unsigned char* ga0 = g8 + (size_t)rec0.y * GDIM + lh * 16;
    const unsigned char* gm1 = g8 + (size_t)rec1.x * GDIM + lh * 16;
    const unsigned char* ga1 = g8 + (size_t)rec1.y * GDIM + lh * 16;

    // stage W1c (80KB) once: 80 chunks, 20/wave
    #pragma unroll
    for (int i = 0; i < 20; i++){
        int c = w * 20 + i;
        glds16(W1c8 + c * 1024 + lane * 16, smem + c * 1024);
    }

    f32x4 acc1[10][2];
    #pragma unroll
    for (int t = 0; t < 10; t++){ acc1[t][0] = (f32x4){0,0,0,0}; acc1[t][1] = (f32x4){0,0,0,0}; }

    asm volatile("s_waitcnt vmcnt(0)" ::: "memory");
    __builtin_amdgcn_s_barrier();

    // ---- GEMM1: barrier-free K-loop, 1-deep A prefetch
    uint4 Rm0 = *reinterpret_cast<const uint4*>(gm0);
    uint4 Ra0 = *reinterpret_cast<const uint4*>(ga0);
    uint4 Rm1 = *reinterpret_cast<const uint4*>(gm1);
    uint4 Ra1 = *reinterpret_cast<const uint4*>(ga1);
    #pragma unroll
    for (int kt = 0; kt < 8; kt++){
        uint4 Nm0, Na0, Nm1, Na1;
        if (kt < 7){
            Nm0 = *reinterpret_cast<const uint4*>(gm0 + (kt+1)*64);
            Na0 = *reinterpret_cast<const uint4*>(ga0 + (kt+1)*64);
            Nm1 = *reinterpret_cast<const uint4*>(gm1 + (kt+1)*64);
            Na1 = *reinterpret_cast<const uint4*>(ga1 + (kt+1)*64);
        }
        uint2 p00 = f8mulpk((uint2){Rm0.x, Rm0.y}, (uint2){Ra0.x, Ra0.y});
        uint2 p01 = f8mulpk((uint2){Rm0.z, Rm0.w}, (uint2){Ra0.z, Ra0.w});
        uint2 p10 = f8mulpk((uint2){Rm1.x, Rm1.y}, (uint2){Ra1.x, Ra1.y});
        uint2 p11 = f8mulpk((uint2){Rm1.z, Rm1.w}, (uint2){Ra1.z, Ra1.w});
        i64 lp00 = u2l(p00), lp01 = u2l(p01), lp10 = u2l(p10), lp11 = u2l(p11);
        __builtin_amdgcn_s_setprio(1);
        #pragma unroll
        for (int t = 0; t < 10; t++){
            int rowb = (t*16 + l15) * 512;
            i64 b0 = *reinterpret_cast<const i64*>(&smem[rowb + ((kt*64 +  0 + lh*8) ^ swz8)]);
            i64 b1 = *reinterpret_cast<const i64*>(&smem[rowb + ((kt*64 + 32 + lh*8) ^ swz8)]);
            acc1[t][0] = mfma8(b0, lp00, acc1[t][0]);
            acc1[t][1] = mfma8(b0, lp10, acc1[t][1]);
            acc1[t][0] = mfma8(b1, lp01, acc1[t][0]);
            acc1[t][1] = mfma8(b1, lp11, acc1[t][1]);
        }
        __builtin_amdgcn_s_setprio(0);
        Rm0 = Nm0; Ra0 = Na0; Rm1 = Nm1; Ra1 = Na1;
    }

    // all waves done reading W1c
    asm volatile("s_waitcnt lgkmcnt(0)" ::: "memory");
    __builtin_amdgcn_s_barrier();

    // stage W2 fp8 (27648B = 27 chunks) into [21504, 49152)
    #pragma unroll
    for (int i = 0; i < 7; i++){
        int c = w * 7 + i;
        if (c < 27) glds16(W28 + c * 1024 + lane * 16, smem + 21504 + c * 1024);
    }

    // ---- epilogue 1: + Am + Aa + PhiW, relu, fp8-pack -> H1 (own-wave slab, stride 168)
    #pragma unroll
    for (int rf = 0; rf < 2; rf++){
        int4 rc = rf ? rec1 : rec0;
        int pr = 32*w + 16*rf + l15;
        const unsigned char* amp = Am + (size_t)rc.x * HIDP;
        const unsigned char* aap = Aa + (size_t)rc.y * HIDP;
        int combo = (rc.z >> 19) & 0xFF;
        const unsigned short* php = PhiW + (size_t)combo * HIDP;
        char* h1row = smem + pr * 168;
        #pragma unroll
        for (int t = 0; t < 10; t++){
            int h0 = 16*t + 4*lh;
            unsigned int amd = *reinterpret_cast<const unsigned int*>(amp + h0);
            unsigned int aad = *reinterpret_cast<const unsigned int*>(aap + h0);
            ushort4 ph4 = *reinterpret_cast<const ushort4*>(php + h0);
            f32x2 amL = __builtin_amdgcn_cvt_pk_f32_fp8(amd, false);
            f32x2 amH = __builtin_amdgcn_cvt_pk_f32_fp8(amd, true);
            f32x2 aaL = __builtin_amdgcn_cvt_pk_f32_fp8(aad, false);
            f32x2 aaH = __builtin_amdgcn_cvt_pk_f32_fp8(aad, true);
            f32x4 a = acc1[t][rf];
            float v0 = fmaxf(a[0] + amL[0] + aaL[0] + bf2f(ph4.x), 0.f);
            float v1 = fmaxf(a[1] + amL[1] + aaL[1] + bf2f(ph4.y), 0.f);
            float v2 = fmaxf(a[2] + amH[0] + aaH[0] + bf2f(ph4.z), 0.f);
            float v3 = fmaxf(a[3] + amH[1] + aaH[1] + bf2f(ph4.w), 0.f);
            unsigned int dw = 0;
            dw = __builtin_amdgcn_cvt_pk_fp8_f32(v0, v1, dw, false);
            dw = __builtin_amdgcn_cvt_pk_fp8_f32(v2, v3, dw, true);
            *reinterpret_cast<unsigned int*>(h1row + h0) = dw;
        }
    }

    // W2 staged by all waves + own H1 written
    asm volatile("s_waitcnt vmcnt(0) lgkmcnt(0)" ::: "memory");
    __builtin_amdgcn_s_barrier();

    // ---- GEMM2: H2 = W2(LDS) x H1(LDS), fp8 MFMA
    f32x4 acc2[10][2];
    #pragma unroll
    for (int t = 0; t < 10; t++){ acc2[t][0] = (f32x4){0,0,0,0}; acc2[t][1] = (f32x4){0,0,0,0}; }
    const char* w2b = smem + 21504;
    __builtin_amdgcn_s_setprio(1);
    #pragma unroll
    for (int k2 = 0; k2 < 5; k2++){
        i64 h0f = *reinterpret_cast<const i64*>(smem + (32*w + l15)      * 168 + k2*32 + lh*8);
        i64 h1f = *reinterpret_cast<const i64*>(smem + (32*w + 16 + l15) * 168 + k2*32 + lh*8);
        #pragma unroll
        for (int t = 0; t < 10; t++){
            i64 wf = *reinterpret_cast<const i64*>(w2b + (16*t + l15) * 168 + k2*32 + lh*8);
            acc2[t][0] = mfma8(wf, h0f, acc2[t][0]);
            acc2[t][1] = mfma8(wf, h1f, acc2[t][1]);
        }
    }
    __builtin_amdgcn_s_setprio(0);

    // ---- epilogue 2: relu(+b2), dot W3, + ms sum, scatter
    float b3v = b3[0];
    #pragma unroll
    for (int rf = 0; rf < 2; rf++){
        int4 rc = rf ? rec1 : rec0;
        float s = 0.f;
        #pragma unroll
        for (int t = 0; t < 10; t++){
            f32x4 w3v = *reinterpret_cast<const f32x4*>(w3p + 16*t + 4*lh);
            f32x4 b2v = *reinterpret_cast<const f32x4*>(b2p + 16*t + 4*lh);
            f32x4 a = acc2[t][rf];
            s += fmaxf(a[0] + b2v[0], 0.f) * w3v[0];
            s += fmaxf(a[1] + b2v[1], 0.f) * w3v[1];
            s += fmaxf(a[2] + b2v[2], 0.f) * w3v[2];
            s += fmaxf(a[3] + b2v[3], 0.f) * w3v[3];
        }
        s += __shfl_xor(s, 16);
        s += __shfl_xor(s, 32);
        if (!(rc.z & 0x80000000) && lh == 0){
            float val = s + b3v + __int_as_float(rc.w);
            dense[(size_t)((rc.z >> 5) & 0x3FFF) * KP1 + (rc.z & 31)] = val;
        }
    }
}

// ---------------------------------------------------------------- phase 4: segment softmax
__global__ void k_softmax(const float* __restrict__ dense, const int* __restrict__ seg_lengths,
                          float* __restrict__ out, int S){
    int wid = threadIdx.x >> 6, lane = threadIdx.x & 63;
    int s = blockIdx.x * 4 + wid;
    if (s >= S) return;
    int len = seg_lengths[s];
    float ninf = -__builtin_inff();
    float val = ninf;
    if (lane < KP1) val = (lane < len) ? dense[(size_t)s * KP1 + lane] : ((lane == len) ? 0.f : ninf);
    float m = val;
    #pragma unroll
    for (int msk = 1; msk < 64; msk <<= 1) m = fmaxf(m, __shfl_xor(m, msk));
    float e = expf(val - m);
    float sum = e;
    #pragma unroll
    for (int msk = 1; msk < 64; msk <<= 1) sum += __shfl_xor(sum, msk);
    if (lane < KP1) out[(size_t)s * KP1 + lane] = (lane > len) ? 1000.f : (e / sum);
}

// ---------------------------------------------------------------- launch
extern "C" void kernel_launch(void* const* d_in, const int* in_sizes, int n_in,
                              void* d_out, int out_size, void* d_ws, size_t ws_size,
                              hipStream_t stream){
    const float* g_i        = (const float*)d_in[0];
    const float* ms         = (const float*)d_in[1];
    const float* dist_emb   = (const float*)d_in[2];
    const float* genre_emb  = (const float*)d_in[3];
    const float* spk_emb    = (const float*)d_in[4];
    const float* W1         = (const float*)d_in[5];
    const float* b1         = (const float*)d_in[6];
    const float* W2         = (const float*)d_in[7];
    const float* b2         = (const float*)d_in[8];
    const float* W3         = (const float*)d_in[9];
    const float* b3         = (const float*)d_in[10];
    const int* mention_ids  = (const int*)d_in[11];
    const int* antecedent_ids = (const int*)d_in[12];
    const int* dist_idx     = (const int*)d_in[13];
    const int* genre_idx    = (const int*)d_in[14];
    const int* spk_idx      = (const int*)d_in[15];
    const int* seg_ids      = (const int*)d_in[16];
    const int* pos_in_seg   = (const int*)d_in[17];
    const int* seg_lengths  = (const int*)d_in[18];
    int P = in_sizes[11];
    int S = in_sizes[18];

    char* ws = (char*)d_ws;
    unsigned char* W18   = (unsigned char*)(ws + 0);         // 3 x 81920 = 245760
    unsigned char* W28   = (unsigned char*)(ws + 245760);    // 27648   -> 273408
    unsigned short* PhiW = (unsigned short*)(ws + 273408);   // 67200   -> 340608
    float* w3pad         = (float*)(ws + 340608);            // 640     -> 341248
    float* b2pad         = (float*)(ws + 341248);            // 640     -> 341888
    unsigned char* g8    = (unsigned char*)(ws + 341888);    // 6144000 -> 6485888
    unsigned char* Am8   = (unsigned char*)(ws + 6485888);   // 1920000 -> 8405888
    unsigned char* Aa8   = (unsigned char*)(ws + 8405888);   // 1920000 -> 10325888
    int* hist            = (int*)(ws + 10325888);            // 48000   -> 10373888
    int* offsw           = (int*)(ws + 10373888);            // 48000   -> 10421888
    int4* recs           = (int4*)(ws + 10421888);           // (P+128)*16 -> <13000192
    float* dense         = (float*)(ws + 13000192);          // 10001*31*4

    int prep_threads = NROWS * 32 + 33600 + HIDP;
    k_prep0<<<(prep_threads + 255)/256, 256, 0, stream>>>(g_i, g8, hist, recs, W1, W18, W2, W28,
        dist_emb, genre_emb, spk_emb, b1, W3, b2, PhiW, w3pad, b2pad, P);
    k_hist<<<(P + 255)/256, 256, 0, stream>>>(mention_ids, hist, P);
    k_scan<<<1, 1024, 0, stream>>>(hist, offsw, NROWS);
    k_scatter<<<(P + 255)/256, 256, 0, stream>>>(mention_ids, antecedent_ids, dist_idx, genre_idx,
        spk_idx, seg_ids, pos_in_seg, ms, offsw, recs, P);

    // row projections Am / Aa (fp8 out; y selects W1a/W1b slice and output half)
    k_proj<<<dim3((NROWS + BMP - 1)/BMP, 2), 256, 0, stream>>>(g8, W18, Am8);

    // fused pair scorer (256 threads, 128 pairs/block)
    k_fused<<<(P + BMF - 1)/BMF, 256, 0, stream>>>(g8, W18 + 2*81920, W28, PhiW,
        Am8, Aa8, w3pad, b2pad, b3, recs, dense);

    // segment softmax
    k_softmax<<<(S + 3)/4, 256, 0, stream>>>(dense, seg_lengths, (float*)d_out, S);
}